// Round 1
// baseline (393.565 us; speedup 1.0000x reference)
//
#include <hip/hip_runtime.h>
#include <math.h>

#define PCEN_EPS 1e-6f

// ===========================================================================
// float4 path (M % 4 == 0): 4 independent scan chains per thread, 16B loads.
// ===========================================================================

// K1: per-(b, chunk, 4-mel-group) local EMA scan starting from m=0.
__global__ void pcen_chunk_scan_v4(const float4* __restrict__ x,
                                   const float* __restrict__ log_s,
                                   float4* __restrict__ contrib,
                                   int B, int T, int M4, int C, int L) {
    int tid = blockIdx.x * blockDim.x + threadIdx.x;
    int total = B * C * M4;
    if (tid >= total) return;
    int g = tid % M4;
    int c = (tid / M4) % C;
    int b = tid / (M4 * C);

    float sx = expf(log_s[4 * g + 0]);
    float sy = expf(log_s[4 * g + 1]);
    float sz = expf(log_s[4 * g + 2]);
    float sw = expf(log_s[4 * g + 3]);
    float ox = 1.0f - sx, oy = 1.0f - sy, oz = 1.0f - sz, ow = 1.0f - sw;

    int start = c * L;
    int len = T - start;
    if (len > L) len = L;
    if (len < 0) len = 0;

    int base = (b * T + start) * M4 + g;
    float mx = 0.0f, my = 0.0f, mz = 0.0f, mw = 0.0f;
#pragma unroll 8
    for (int i = 0; i < len; ++i) {
        float4 xv = x[base];
        mx = fmaf(ox, mx, sx * xv.x);
        my = fmaf(oy, my, sy * xv.y);
        mz = fmaf(oz, mz, sz * xv.z);
        mw = fmaf(ow, mw, sw * xv.w);
        base += M4;
    }
    float4 o;
    o.x = mx; o.y = my; o.z = mz; o.w = mw;
    contrib[tid] = o;  // layout [b][c][g]
}

// K2: per-(b, 4-mel-group) serial prefix over the C chunks.
__global__ void pcen_chunk_prefix_v4(const float4* __restrict__ contrib,
                                     const float* __restrict__ log_s,
                                     float4* __restrict__ m_start,
                                     int B, int T, int M4, int C, int L) {
    int tid = blockIdx.x * blockDim.x + threadIdx.x;
    if (tid >= B * M4) return;
    int g = tid % M4;
    int b = tid / M4;

    float sx = expf(log_s[4 * g + 0]);
    float sy = expf(log_s[4 * g + 1]);
    float sz = expf(log_s[4 * g + 2]);
    float sw = expf(log_s[4 * g + 3]);
    float ox = 1.0f - sx, oy = 1.0f - sy, oz = 1.0f - sz, ow = 1.0f - sw;
    float dxf = powf(ox, (float)L);
    float dyf = powf(oy, (float)L);
    float dzf = powf(oz, (float)L);
    float dwf = powf(ow, (float)L);

    int base = b * C * M4 + g;
    float mx = 0.0f, my = 0.0f, mz = 0.0f, mw = 0.0f;
#pragma unroll 4
    for (int c = 0; c < C; ++c) {
        float4 o;
        o.x = mx; o.y = my; o.z = mz; o.w = mw;
        m_start[base + c * M4] = o;

        int start = c * L;
        int len = T - start;
        if (len > L) len = L;
        if (len < 0) len = 0;

        float fx = dxf, fy = dyf, fz = dzf, fw = dwf;
        if (len != L) {
            fx = powf(ox, (float)len);
            fy = powf(oy, (float)len);
            fz = powf(oz, (float)len);
            fw = powf(ow, (float)len);
        }
        float4 cv = contrib[base + c * M4];
        mx = fmaf(fx, mx, cv.x);
        my = fmaf(fy, my, cv.y);
        mz = fmaf(fz, mz, cv.z);
        mw = fmaf(fw, mw, cv.w);
    }
}

// K3: re-scan with correct start state + PCEN epilogue, float4 in/out.
__global__ void pcen_output_v4(const float4* __restrict__ x,
                               const float* __restrict__ log_s,
                               const float* __restrict__ log_alpha,
                               const float* __restrict__ log_delta,
                               const float* __restrict__ log_r,
                               const float4* __restrict__ m_start,
                               float4* __restrict__ out,
                               int B, int T, int M4, int C, int L) {
    int tid = blockIdx.x * blockDim.x + threadIdx.x;
    int total = B * C * M4;
    if (tid >= total) return;
    int g = tid % M4;
    int c = (tid / M4) % C;
    int b = tid / (M4 * C);

    float sx = expf(log_s[4 * g + 0]);
    float sy = expf(log_s[4 * g + 1]);
    float sz = expf(log_s[4 * g + 2]);
    float sw = expf(log_s[4 * g + 3]);
    float ox = 1.0f - sx, oy = 1.0f - sy, oz = 1.0f - sz, ow = 1.0f - sw;

    float ax = expf(log_alpha[4 * g + 0]);
    float ay = expf(log_alpha[4 * g + 1]);
    float az = expf(log_alpha[4 * g + 2]);
    float aw = expf(log_alpha[4 * g + 3]);

    float dx = expf(log_delta[4 * g + 0]);
    float dy = expf(log_delta[4 * g + 1]);
    float dz = expf(log_delta[4 * g + 2]);
    float dw = expf(log_delta[4 * g + 3]);

    float rx = expf(log_r[4 * g + 0]);
    float ry = expf(log_r[4 * g + 1]);
    float rz = expf(log_r[4 * g + 2]);
    float rw = expf(log_r[4 * g + 3]);

    float drx = powf(dx, rx);
    float dry = powf(dy, ry);
    float drz = powf(dz, rz);
    float drw = powf(dw, rw);

    int start = c * L;
    int len = T - start;
    if (len > L) len = L;
    if (len < 0) len = 0;

    float4 m0 = m_start[tid];
    float mx = m0.x, my = m0.y, mz = m0.z, mw = m0.w;

    int base = (b * T + start) * M4 + g;
#pragma unroll 4
    for (int i = 0; i < len; ++i) {
        float4 xv = x[base];
        mx = fmaf(ox, mx, sx * xv.x);
        my = fmaf(oy, my, sy * xv.y);
        mz = fmaf(oz, mz, sz * xv.z);
        mw = fmaf(ow, mw, sw * xv.w);

        float4 o;
        float px = __expf(-ax * __logf(mx + PCEN_EPS));
        float py = __expf(-ay * __logf(my + PCEN_EPS));
        float pz = __expf(-az * __logf(mz + PCEN_EPS));
        float pw = __expf(-aw * __logf(mw + PCEN_EPS));
        float yx = fmaf(xv.x, px, dx);
        float yy = fmaf(xv.y, py, dy);
        float yz = fmaf(xv.z, pz, dz);
        float yw = fmaf(xv.w, pw, dw);
        o.x = __expf(rx * __logf(yx)) - drx;
        o.y = __expf(ry * __logf(yy)) - dry;
        o.z = __expf(rz * __logf(yz)) - drz;
        o.w = __expf(rw * __logf(yw)) - drw;

        out[base] = o;
        base += M4;
    }
}

// ===========================================================================
// scalar fallback (M % 4 != 0) — identical to previous verified version.
// ===========================================================================

__global__ void pcen_chunk_scan(const float* __restrict__ x,
                                const float* __restrict__ log_s,
                                float* __restrict__ contrib,
                                int B, int T, int M, int C, int L) {
    int tid = blockIdx.x * blockDim.x + threadIdx.x;
    int total = B * C * M;
    if (tid >= total) return;
    int mi = tid % M;
    int c  = (tid / M) % C;
    int b  = tid / (M * C);

    float s   = expf(log_s[mi]);
    float oms = 1.0f - s;

    int start = c * L;
    int len = T - start;
    if (len > L) len = L;
    if (len < 0) len = 0;

    int base = (b * T + start) * M + mi;
    float m = 0.0f;
#pragma unroll 4
    for (int i = 0; i < len; ++i) {
        m = fmaf(oms, m, s * x[base]);
        base += M;
    }
    contrib[tid] = m;
}

__global__ void pcen_chunk_prefix(const float* __restrict__ contrib,
                                  const float* __restrict__ log_s,
                                  float* __restrict__ m_start,
                                  int B, int T, int M, int C, int L) {
    int tid = blockIdx.x * blockDim.x + threadIdx.x;
    if (tid >= B * M) return;
    int mi = tid % M;
    int b  = tid / M;

    float s   = expf(log_s[mi]);
    float oms = 1.0f - s;
    float dL_full = powf(oms, (float)L);

    int base = b * C * M + mi;
    float m = 0.0f;
    for (int c = 0; c < C; ++c) {
        m_start[base + c * M] = m;
        int start = c * L;
        int len = T - start;
        if (len > L) len = L;
        if (len < 0) len = 0;
        float dL = (len == L) ? dL_full : powf(oms, (float)len);
        m = fmaf(dL, m, contrib[base + c * M]);
    }
}

__global__ void pcen_output(const float* __restrict__ x,
                            const float* __restrict__ log_s,
                            const float* __restrict__ log_alpha,
                            const float* __restrict__ log_delta,
                            const float* __restrict__ log_r,
                            const float* __restrict__ m_start,
                            float* __restrict__ out,
                            int B, int T, int M, int C, int L) {
    int tid = blockIdx.x * blockDim.x + threadIdx.x;
    int total = B * C * M;
    if (tid >= total) return;
    int mi = tid % M;
    int c  = (tid / M) % C;
    int b  = tid / (M * C);

    float s     = expf(log_s[mi]);
    float alpha = expf(log_alpha[mi]);
    float delta = expf(log_delta[mi]);
    float r     = expf(log_r[mi]);
    float delta_r = powf(delta, r);
    float oms   = 1.0f - s;

    int start = c * L;
    int len = T - start;
    if (len > L) len = L;
    if (len < 0) len = 0;

    float m = m_start[tid];
    int base = (b * T + start) * M + mi;
#pragma unroll 4
    for (int i = 0; i < len; ++i) {
        float xv = x[base];
        m = fmaf(oms, m, s * xv);
        float p = __expf(-alpha * __logf(m + PCEN_EPS));
        float y = fmaf(xv, p, delta);
        out[base] = __expf(r * __logf(y)) - delta_r;
        base += M;
    }
}

extern "C" void kernel_launch(void* const* d_in, const int* in_sizes, int n_in,
                              void* d_out, int out_size, void* d_ws, size_t ws_size,
                              hipStream_t stream) {
    const float* x         = (const float*)d_in[0];
    const float* log_s     = (const float*)d_in[1];
    const float* log_alpha = (const float*)d_in[2];
    const float* log_delta = (const float*)d_in[3];
    const float* log_r     = (const float*)d_in[4];
    float* out = (float*)d_out;

    const int M = in_sizes[1];            // 80
    const int B = 64;                     // per reference setup
    const int T = in_sizes[0] / (B * M);  // 8000

    // C=200 -> L=40: with float4 merge this keeps B*C*(M/4)=256k threads
    // (~16 waves/CU) while quadrupling in-flight load bytes per thread.
    int C = 200;
    while (C > 1 && (size_t)(2ll * B * C * M * 4) > ws_size) C--;
    const int L = (T + C - 1) / C;

    float* contrib = (float*)d_ws;                 // B*C*M floats
    float* mstart  = contrib + (size_t)B * C * M;  // B*C*M floats

    const int threads = 256;

    if ((M & 3) == 0) {
        const int M4 = M / 4;
        int total1 = B * C * M4;
        int total2 = B * M4;
        pcen_chunk_scan_v4<<<(total1 + threads - 1) / threads, threads, 0, stream>>>(
            (const float4*)x, log_s, (float4*)contrib, B, T, M4, C, L);
        pcen_chunk_prefix_v4<<<(total2 + threads - 1) / threads, threads, 0, stream>>>(
            (const float4*)contrib, log_s, (float4*)mstart, B, T, M4, C, L);
        pcen_output_v4<<<(total1 + threads - 1) / threads, threads, 0, stream>>>(
            (const float4*)x, log_s, log_alpha, log_delta, log_r,
            (const float4*)mstart, (float4*)out, B, T, M4, C, L);
    } else {
        int total1 = B * C * M;
        int total2 = B * M;
        pcen_chunk_scan<<<(total1 + threads - 1) / threads, threads, 0, stream>>>(
            x, log_s, contrib, B, T, M, C, L);
        pcen_chunk_prefix<<<(total2 + threads - 1) / threads, threads, 0, stream>>>(
            contrib, log_s, mstart, B, T, M, C, L);
        pcen_output<<<(total1 + threads - 1) / threads, threads, 0, stream>>>(
            x, log_s, log_alpha, log_delta, log_r, mstart, out, B, T, M, C, L);
    }
}